// Round 2
// baseline (32846.359 us; speedup 1.0000x reference)
//
#include <hip/hip_runtime.h>

#define HH 51
#define TT 256
#define NB 16          // batch elements per workgroup
#define NJG 32         // gate-row groups (thread dim)
#define NROW 7         // gate rows per thread (32*7 = 224 >= 204, zero-padded)

// ---------------- activation helpers (fp32, safe-clamped) ----------------
__device__ __forceinline__ float sigm(float x) {
    return 1.0f / (1.0f + __expf(-x));
}
__device__ __forceinline__ float tanh_fast(float x) {
    x = fminf(15.0f, fmaxf(-15.0f, x));
    float e = __expf(2.0f * x);
    return (e - 1.0f) / (e + 1.0f);
}

// ---------------- weight repack ------------------------------------------
// Layouts (zero-padded, branch-free main loop), j = jg + 32*m:
//  W1r[(k4*7 + m)*32 + jg] : float4 = W_hh1[j][4k4..4k4+3], k4 in [0,13)
//  W2r[(kq*7 + m)*32 + jg] : kq<13 -> W_ih2[j][4kq..], kq>=13 -> W_hh2[j][4(kq-13)..]
//  wx/bb1/bb2[m*32 + jg]
__global__ void lstm_prep(const float* __restrict__ Wih1, const float* __restrict__ Whh1,
                          const float* __restrict__ bih1, const float* __restrict__ bhh1,
                          const float* __restrict__ Wih2, const float* __restrict__ Whh2,
                          const float* __restrict__ bih2, const float* __restrict__ bhh2,
                          float4* __restrict__ W1r, float4* __restrict__ W2r,
                          float* __restrict__ wx, float* __restrict__ bb1,
                          float* __restrict__ bb2) {
    int tid = blockIdx.x * blockDim.x + threadIdx.x;
    int stride = gridDim.x * blockDim.x;

    // W1r: 13*7*32 = 2912 float4
    for (int e = tid; e < 13 * 7 * 32; e += stride) {
        int jg = e & 31, q = e >> 5;
        int m = q % 7, k4 = q / 7;
        int j = jg + 32 * m;
        float t[4] = {0.f, 0.f, 0.f, 0.f};
        if (j < 4 * HH) {
            for (int c = 0; c < 4; c++) {
                int k = 4 * k4 + c;
                if (k < HH) t[c] = Whh1[j * HH + k];
            }
        }
        W1r[e] = make_float4(t[0], t[1], t[2], t[3]);
    }
    // W2r: 26*7*32 = 5824 float4
    for (int e = tid; e < 26 * 7 * 32; e += stride) {
        int jg = e & 31, q = e >> 5;
        int m = q % 7, kq = q / 7;
        int j = jg + 32 * m;
        float t[4] = {0.f, 0.f, 0.f, 0.f};
        if (j < 4 * HH) {
            for (int c = 0; c < 4; c++) {
                int kk = 4 * kq + c;
                if (kk < 52) {
                    if (kk < HH) t[c] = Wih2[j * HH + kk];
                } else {
                    int k = kk - 52;
                    if (k < HH) t[c] = Whh2[j * HH + k];
                }
            }
        }
        W2r[e] = make_float4(t[0], t[1], t[2], t[3]);
    }
    for (int e = tid; e < NJG * NROW; e += stride) {
        int jg = e & 31, m = e >> 5;
        int j = jg + 32 * m;
        bool ok = (j < 4 * HH);
        wx[e]  = ok ? Wih1[j] : 0.f;
        bb1[e] = ok ? (bih1[j] + bhh1[j]) : 0.f;
        bb2[e] = ok ? (bih2[j] + bhh2[j]) : 0.f;
    }
}

// ---------------- persistent LSTM kernel: 1 WG = 16 batch, 512 threads ----
__launch_bounds__(512, 2)
__global__ void lstm_main(const float* __restrict__ input,
                          const float4* __restrict__ W1r, const float4* __restrict__ W2r,
                          const float* __restrict__ wx_g, const float* __restrict__ bb1_g,
                          const float* __restrict__ bb2_g,
                          const float* __restrict__ Wlin, const float* __restrict__ blin,
                          float* __restrict__ out) {
    __shared__ __align__(16) float h1[NB * 52];
    __shared__ __align__(16) float h2[NB * 52];
    __shared__ float c1[HH * NB];
    __shared__ float c2[HH * NB];
    __shared__ float gates[NJG * NROW * NB];   // 224 rows x 16 batch
    __shared__ __align__(16) float wl[52];

    const int tid = threadIdx.x;
    const int b  = tid & 15;
    const int jg = tid >> 4;                   // 0..31
    const int b0 = blockIdx.x * NB;

    for (int i = tid; i < NB * 52; i += 512) { h1[i] = 0.f; h2[i] = 0.f; }
    for (int i = tid; i < HH * NB; i += 512) { c1[i] = 0.f; c2[i] = 0.f; }
    if (tid < 52) wl[tid] = (tid < HH) ? Wlin[tid] : 0.f;

    float wxr[NROW], B1[NROW], B2[NROW];
#pragma unroll
    for (int m = 0; m < NROW; m++) {
        wxr[m] = wx_g[m * 32 + jg];
        B1[m]  = bb1_g[m * 32 + jg];
        B2[m]  = bb2_g[m * 32 + jg];
    }
    const float bl = blin[0];
    const float* xrow = input + (size_t)(b0 + b) * TT;
    float xs_cur = xrow[0];

    __syncthreads();

    for (int t = 0; t < TT; t++) {
        // ---------------- cell1 gates (pipelined weight stream) -----------
        float acc[NROW];
#pragma unroll
        for (int m = 0; m < NROW; m++) acc[m] = fmaf(xs_cur, wxr[m], B1[m]);
        xs_cur = xrow[(t + 1 < TT) ? t + 1 : t];   // prefetch next step's x

        {
            float4 w[NROW], wn[NROW];
#pragma unroll
            for (int m = 0; m < NROW; m++) w[m] = W1r[m * NJG + jg];
            float4 hv = *(const float4*)&h1[b * 52];
            float4 hvn;
#pragma unroll
            for (int k4 = 0; k4 < 13; k4++) {
                if (k4 < 12) {
#pragma unroll
                    for (int m = 0; m < NROW; m++)
                        wn[m] = W1r[((k4 + 1) * NROW + m) * NJG + jg];
                    hvn = *(const float4*)&h1[b * 52 + 4 * (k4 + 1)];
                }
#pragma unroll
                for (int m = 0; m < NROW; m++)
                    acc[m] = fmaf(w[m].x, hv.x, fmaf(w[m].y, hv.y,
                             fmaf(w[m].z, hv.z, fmaf(w[m].w, hv.w, acc[m]))));
                if (k4 < 12) {
#pragma unroll
                    for (int m = 0; m < NROW; m++) w[m] = wn[m];
                    hv = hvn;
                }
            }
        }
#pragma unroll
        for (int m = 0; m < NROW; m++) gates[(jg + NJG * m) * NB + b] = acc[m];
        __syncthreads();

        // ---------------- cell1 update ------------------------------------
        for (int r = tid; r < NB * HH; r += 512) {
            int u = r >> 4, bb = r & 15;
            float ii = gates[u * 16 + bb];
            float ff = gates[(HH + u) * 16 + bb];
            float gg = gates[(2 * HH + u) * 16 + bb];
            float oo = gates[(3 * HH + u) * 16 + bb];
            float c = c1[u * 16 + bb];
            float cn = sigm(ff) * c + sigm(ii) * tanh_fast(gg);
            c1[u * 16 + bb] = cn;
            h1[bb * 52 + u] = sigm(oo) * tanh_fast(cn);
        }
        __syncthreads();

        // ---------------- cell2 gates: K = [h1_new | h2], pipelined -------
#pragma unroll
        for (int m = 0; m < NROW; m++) acc[m] = B2[m];
        {
            float4 w[NROW], wn[NROW];
#pragma unroll
            for (int m = 0; m < NROW; m++) w[m] = W2r[m * NJG + jg];
            float4 hv = *(const float4*)&h1[b * 52];
            float4 hvn;
#pragma unroll
            for (int kq = 0; kq < 26; kq++) {
                if (kq < 25) {
#pragma unroll
                    for (int m = 0; m < NROW; m++)
                        wn[m] = W2r[((kq + 1) * NROW + m) * NJG + jg];
                    int kn = kq + 1;
                    hvn = (kn < 13) ? *(const float4*)&h1[b * 52 + 4 * kn]
                                    : *(const float4*)&h2[b * 52 + 4 * (kn - 13)];
                }
#pragma unroll
                for (int m = 0; m < NROW; m++)
                    acc[m] = fmaf(w[m].x, hv.x, fmaf(w[m].y, hv.y,
                             fmaf(w[m].z, hv.z, fmaf(w[m].w, hv.w, acc[m]))));
                if (kq < 25) {
#pragma unroll
                    for (int m = 0; m < NROW; m++) w[m] = wn[m];
                    hv = hvn;
                }
            }
        }
#pragma unroll
        for (int m = 0; m < NROW; m++) gates[(jg + NJG * m) * NB + b] = acc[m];
        __syncthreads();

        // ---------------- cell2 update ------------------------------------
        for (int r = tid; r < NB * HH; r += 512) {
            int u = r >> 4, bb = r & 15;
            float ii = gates[u * 16 + bb];
            float ff = gates[(HH + u) * 16 + bb];
            float gg = gates[(2 * HH + u) * 16 + bb];
            float oo = gates[(3 * HH + u) * 16 + bb];
            float c = c2[u * 16 + bb];
            float cn = sigm(ff) * c + sigm(ii) * tanh_fast(gg);
            c2[u * 16 + bb] = cn;
            h2[bb * 52 + u] = sigm(oo) * tanh_fast(cn);
        }
        __syncthreads();

        // ---------------- head: out[b][t] = W_lin . h2 + b_lin -------------
        if (tid < NB) {
            const float4* hr  = (const float4*)&h2[tid * 52];
            const float4* wl4 = (const float4*)wl;
            float a = bl;
#pragma unroll
            for (int k4 = 0; k4 < 13; k4++) {
                float4 hv = hr[k4], wv = wl4[k4];
                a = fmaf(wv.x, hv.x, fmaf(wv.y, hv.y,
                    fmaf(wv.z, hv.z, fmaf(wv.w, hv.w, a))));
            }
            out[(size_t)(b0 + tid) * TT + t] = a;
        }
        // no extra barrier: next cell1 reads h1 (stable until next update1)
        // and writes gates (fully consumed before the update2 barrier).
    }
}

extern "C" void kernel_launch(void* const* d_in, const int* in_sizes, int n_in,
                              void* d_out, int out_size, void* d_ws, size_t ws_size,
                              hipStream_t stream) {
    const float* input = (const float*)d_in[0];
    const float* Wih1  = (const float*)d_in[1];
    const float* Whh1  = (const float*)d_in[2];
    const float* bih1  = (const float*)d_in[3];
    const float* bhh1  = (const float*)d_in[4];
    const float* Wih2  = (const float*)d_in[5];
    const float* Whh2  = (const float*)d_in[6];
    const float* bih2  = (const float*)d_in[7];
    const float* bhh2  = (const float*)d_in[8];
    const float* Wlin  = (const float*)d_in[9];
    const float* blin  = (const float*)d_in[10];

    float* ws = (float*)d_ws;
    float4* W1r = (float4*)ws;                      // 13*7*32 = 2912 float4 = 11648 f
    float4* W2r = (float4*)(ws + 11648);            // 26*7*32 = 5824 float4 = 23296 f
    float* wx  = ws + 11648 + 23296;                // 224
    float* bb1 = wx + 224;                          // 224
    float* bb2 = bb1 + 224;                         // 224

    int B = in_sizes[0] / TT;                       // 4096

    lstm_prep<<<64, 256, 0, stream>>>(Wih1, Whh1, bih1, bhh1, Wih2, Whh2, bih2, bhh2,
                                      W1r, W2r, wx, bb1, bb2);
    lstm_main<<<B / NB, 512, 0, stream>>>(input, W1r, W2r, wx, bb1, bb2, Wlin, blin,
                                          (float*)d_out);
}

// Round 3
// 893.515 us; speedup vs baseline: 36.7608x; 36.7608x over previous
//
#include <hip/hip_runtime.h>

#define HH 51
#define TT 256
#define NB 16

// MFMA fragment types (gfx950: bf16 builtins take v8bf16)
typedef __attribute__((ext_vector_type(8))) __bf16 bf16x8;
typedef __attribute__((ext_vector_type(4))) float  floatx4;

__device__ __forceinline__ unsigned short f2bf(float f) {
    unsigned u = __float_as_uint(f);
    unsigned r = (u + 0x7FFFu + ((u >> 16) & 1u)) >> 16;   // round-to-nearest-even
    return (unsigned short)r;
}
__device__ __forceinline__ float bf2f(unsigned short h) {
    return __uint_as_float(((unsigned)h) << 16);
}
__device__ __forceinline__ float sigm(float x) { return 1.0f / (1.0f + __expf(-x)); }
__device__ __forceinline__ float tanh_fast(float x) {
    x = fminf(15.0f, fmaxf(-15.0f, x));
    float e = __expf(2.0f * x);
    return (e - 1.0f) / (e + 1.0f);
}

// -------------------------------------------------------------------------
// Weight pre-pack into MFMA B-fragments (hi/lo bf16 split), zero-padded.
// Tile tau = g*4 + U (g=gate 0..3, U=u-group 0..3); within-tile col n = u&15.
// B-frag layout for 16x16x32 (verified m89/m120 duality): lane holds
// B[k = (lane>>4)*8 + jj][n = lane&15], 8 bf16 = 16 B.
// frag id f: cell1 (K=64, 2 ksteps): f = (tau*2+s)*2 + hl          (64 frags)
//            cell2 (K=128, 4 ksteps): f = 64 + (tau*4+s)*2 + hl    (128 frags)
// ws bytes needed: 192 frags * 64 lanes * 16 B = 196608.
// -------------------------------------------------------------------------
__global__ void lstm_prep(const float* __restrict__ Whh1,
                          const float* __restrict__ Wih2, const float* __restrict__ Whh2,
                          uint4* __restrict__ frags) {
    int tid = blockIdx.x * blockDim.x + threadIdx.x;
    if (tid >= 192 * 64) return;
    int f = tid >> 6, lane = tid & 63;
    int n = lane & 15, qq = lane >> 4;
    int hl, s, tau, cell;
    if (f < 64) { cell = 1; int r = f;      hl = r & 1; r >>= 1; s = r & 1; tau = r >> 1; }
    else        { cell = 2; int r = f - 64; hl = r & 1; r >>= 1; s = r & 3; tau = r >> 2; }
    int g = tau >> 2, U = tau & 3, u = U * 16 + n;
    bool valid = (u < HH);
    int jrow = g * HH + u;                       // gate-row in original i,f,g,o stacking
    unsigned int dw[4];
    for (int d = 0; d < 4; d++) {
        unsigned int packed = 0;
        for (int e = 0; e < 2; e++) {
            int jj = d * 2 + e;
            int k = s * 32 + qq * 8 + jj;
            float val = 0.f;
            if (valid) {
                if (cell == 1) {
                    if (k < HH) val = Whh1[jrow * HH + k];
                } else {
                    if (k < 64) { if (k < HH) val = Wih2[jrow * HH + k]; }
                    else { int k2 = k - 64; if (k2 < HH) val = Whh2[jrow * HH + k2]; }
                }
            }
            unsigned short hi = f2bf(val);
            unsigned short bits = hl ? f2bf(val - bf2f(hi)) : hi;
            packed |= ((unsigned int)bits) << (16 * e);
        }
        dw[d] = packed;
    }
    frags[f * 64 + lane] = make_uint4(dw[0], dw[1], dw[2], dw[3]);
}

// -------------------------------------------------------------------------
// Persistent LSTM: 1 WG = 16 batch, 256 thr = 4 waves. Wave U owns u-range
// [16U, 16U+16) for ALL four gates (tiles U, 4+U, 8+U, 12+U) -> i,f,g,o and
// c stay in registers; h round-trips LDS as bf16 hi/lo in A-frag layout.
// A-frag (m120): lane reads A[m = lane&15 = batch][k = quad*8 + j].
// C/D (m89/m91): col = lane&15 = u-col, row = quad*4 + reg = batch.
// h rows stride 72 ushorts (144 B): bank group (4b+4q)%32 -> 2-way = free.
// -------------------------------------------------------------------------
__launch_bounds__(256, 1)
__global__ void lstm_main(const float* __restrict__ input,
                          const uint4* __restrict__ frags,
                          const float* __restrict__ Wih1,
                          const float* __restrict__ bih1, const float* __restrict__ bhh1,
                          const float* __restrict__ bih2, const float* __restrict__ bhh2,
                          const float* __restrict__ Wlin, const float* __restrict__ blin,
                          float* __restrict__ out) {
    __shared__ __align__(16) unsigned short h1h[2][16][72];
    __shared__ __align__(16) unsigned short h1l[2][16][72];
    __shared__ __align__(16) unsigned short h2h[2][16][72];
    __shared__ __align__(16) unsigned short h2l[2][16][72];
    __shared__ float xb[16 * 257];          // x staged: [b][t], stride 257 vs bank hits
    __shared__ float partial[HH * 17];      // head partials [u][b], stride 17
    __shared__ float p2[4 * 17];

    const int tid  = threadIdx.x;
    const int lane = tid & 63;
    const int U    = tid >> 6;              // wave id = u-group
    const int l15  = tid & 15;
    const int q    = (tid >> 4) & 3;        // quad within wave
    const int u    = U * 16 + l15;
    const bool valid = (u < HH);
    const int b0 = blockIdx.x * NB;

    // zero h buffers (pad cols k>=51 must stay zero for MFMA correctness)
    for (int i = tid; i < 2 * 16 * 72; i += 256) {
        ((unsigned short*)h1h)[i] = 0; ((unsigned short*)h1l)[i] = 0;
        ((unsigned short*)h2h)[i] = 0; ((unsigned short*)h2l)[i] = 0;
    }
    // stage x into LDS (coalesced float4 global reads)
    for (int c = 0; c < 4; c++) {
        int flat = (tid + c * 256) * 4;
        int b = flat >> 8, t0 = flat & 255;
        float4 v = *(const float4*)&input[(size_t)(b0 + b) * TT + t0];
        xb[b * 257 + t0 + 0] = v.x;
        xb[b * 257 + t0 + 1] = v.y;
        xb[b * 257 + t0 + 2] = v.z;
        xb[b * 257 + t0 + 3] = v.w;
    }

    // weight-stationary B-fragments (one-time coalesced loads, then registers)
    bf16x8 B1h[4][2], B1l[4][2], B2h[4][4], B2l[4][4];
#pragma unroll
    for (int g = 0; g < 4; g++) {
        int tau = g * 4 + U;
#pragma unroll
        for (int s = 0; s < 2; s++) {
            B1h[g][s] = __builtin_bit_cast(bf16x8, frags[(((tau * 2 + s) * 2) + 0) * 64 + lane]);
            B1l[g][s] = __builtin_bit_cast(bf16x8, frags[(((tau * 2 + s) * 2) + 1) * 64 + lane]);
        }
#pragma unroll
        for (int s = 0; s < 4; s++) {
            B2h[g][s] = __builtin_bit_cast(bf16x8, frags[(64 + ((tau * 4 + s) * 2) + 0) * 64 + lane]);
            B2l[g][s] = __builtin_bit_cast(bf16x8, frags[(64 + ((tau * 4 + s) * 2) + 1) * 64 + lane]);
        }
    }
    // per-lane scalars (index by u = within-tile col, matches C/D col = lane&15)
    float wxv[4], b1v[4], b2v[4];
#pragma unroll
    for (int g = 0; g < 4; g++) {
        int jrow = g * HH + u;
        wxv[g] = valid ? Wih1[jrow] : 0.f;
        b1v[g] = valid ? (bih1[jrow] + bhh1[jrow]) : 0.f;
        b2v[g] = valid ? (bih2[jrow] + bhh2[jrow]) : 0.f;
    }
    const float wlu = valid ? Wlin[u] : 0.f;
    const float bl  = blin[0];
    floatx4 c1r = {0.f, 0.f, 0.f, 0.f}, c2r = {0.f, 0.f, 0.f, 0.f};

    __syncthreads();

    for (int t = 0; t < TT; t++) {
        const int p = t & 1, pn = 1 - p;

        float xr[4];
#pragma unroll
        for (int r = 0; r < 4; r++) xr[r] = xb[(q * 4 + r) * 257 + t];

        // ---------------- cell1: G1 = x*Wih1 + b + h1·Whh1^T (MFMA) -------
        floatx4 a1[4];
#pragma unroll
        for (int g = 0; g < 4; g++) {
            floatx4 a;
#pragma unroll
            for (int r = 0; r < 4; r++) a[r] = fmaf(xr[r], wxv[g], b1v[g]);
            a1[g] = a;
        }
#pragma unroll
        for (int s = 0; s < 2; s++) {
            bf16x8 ah = *(const bf16x8*)&h1h[p][l15][s * 32 + q * 8];
            bf16x8 al = *(const bf16x8*)&h1l[p][l15][s * 32 + q * 8];
#pragma unroll
            for (int g = 0; g < 4; g++) {
                a1[g] = __builtin_amdgcn_mfma_f32_16x16x32_bf16(ah, B1h[g][s], a1[g], 0, 0, 0);
                a1[g] = __builtin_amdgcn_mfma_f32_16x16x32_bf16(ah, B1l[g][s], a1[g], 0, 0, 0);
                a1[g] = __builtin_amdgcn_mfma_f32_16x16x32_bf16(al, B1h[g][s], a1[g], 0, 0, 0);
            }
        }
        // in-register activation; lane owns (b = q*4+r, u) with i,f,g,o local
#pragma unroll
        for (int r = 0; r < 4; r++) {
            float cn = sigm(a1[1][r]) * c1r[r] + sigm(a1[0][r]) * tanh_fast(a1[2][r]);
            c1r[r] = cn;
            float h = sigm(a1[3][r]) * tanh_fast(cn);
            if (valid) {
                int b = q * 4 + r;
                unsigned short hh = f2bf(h);
                h1h[pn][b][u] = hh;
                h1l[pn][b][u] = f2bf(h - bf2f(hh));
            }
        }
        __syncthreads();

        // ---------------- cell2: K = [h1(new) | h2(old)] ------------------
        floatx4 a2[4];
#pragma unroll
        for (int g = 0; g < 4; g++) {
            floatx4 a = {b2v[g], b2v[g], b2v[g], b2v[g]};
            a2[g] = a;
        }
#pragma unroll
        for (int s = 0; s < 4; s++) {
            bf16x8 ah, al;
            if (s < 2) {
                ah = *(const bf16x8*)&h1h[pn][l15][s * 32 + q * 8];
                al = *(const bf16x8*)&h1l[pn][l15][s * 32 + q * 8];
            } else {
                ah = *(const bf16x8*)&h2h[p][l15][(s - 2) * 32 + q * 8];
                al = *(const bf16x8*)&h2l[p][l15][(s - 2) * 32 + q * 8];
            }
#pragma unroll
            for (int g = 0; g < 4; g++) {
                a2[g] = __builtin_amdgcn_mfma_f32_16x16x32_bf16(ah, B2h[g][s], a2[g], 0, 0, 0);
                a2[g] = __builtin_amdgcn_mfma_f32_16x16x32_bf16(ah, B2l[g][s], a2[g], 0, 0, 0);
                a2[g] = __builtin_amdgcn_mfma_f32_16x16x32_bf16(al, B2h[g][s], a2[g], 0, 0, 0);
            }
        }
#pragma unroll
        for (int r = 0; r < 4; r++) {
            float cn = sigm(a2[1][r]) * c2r[r] + sigm(a2[0][r]) * tanh_fast(a2[2][r]);
            c2r[r] = cn;
            float h = sigm(a2[3][r]) * tanh_fast(cn);
            if (valid) {
                int b = q * 4 + r;
                unsigned short hh = f2bf(h);
                h2h[pn][b][u] = hh;
                h2l[pn][b][u] = f2bf(h - bf2f(hh));
                partial[u * 17 + b] = wlu * h;   // head contribution, fp32 h
            }
        }
        __syncthreads();

        // ---------------- head: out[b][t] = bl + sum_u wl[u] h2[b][u] -----
        // two-level reduce inside wave 0 (in-wave LDS ordering is program order)
        if (tid < 64) {
            float s = 0.f;
#pragma unroll
            for (int m = 0; m < 13; m++) {
                int uu = q + 4 * m;
                if (uu < HH) s += partial[uu * 17 + l15];
            }
            p2[q * 17 + l15] = s;
        }
        if (tid < 16) {
            float a = bl + p2[tid] + p2[17 + tid] + p2[34 + tid] + p2[51 + tid];
            out[(size_t)(b0 + tid) * TT + t] = a;
        }
        // partial/p2 rewritten only after the next step's barriers -> no race
    }
}

extern "C" void kernel_launch(void* const* d_in, const int* in_sizes, int n_in,
                              void* d_out, int out_size, void* d_ws, size_t ws_size,
                              hipStream_t stream) {
    const float* input = (const float*)d_in[0];
    const float* Wih1  = (const float*)d_in[1];
    const float* Whh1  = (const float*)d_in[2];
    const float* bih1  = (const float*)d_in[3];
    const float* bhh1  = (const float*)d_in[4];
    const float* Wih2  = (const float*)d_in[5];
    const float* Whh2  = (const float*)d_in[6];
    const float* bih2  = (const float*)d_in[7];
    const float* bhh2  = (const float*)d_in[8];
    const float* Wlin  = (const float*)d_in[9];
    const float* blin  = (const float*)d_in[10];

    uint4* frags = (uint4*)d_ws;            // 192 frags * 1 KiB = 196608 B of ws
    int B = in_sizes[0] / TT;               // 4096

    lstm_prep<<<48, 256, 0, stream>>>(Whh1, Wih2, Whh2, frags);
    lstm_main<<<B / NB, 256, 0, stream>>>(input, frags, Wih1, bih1, bhh1,
                                          bih2, bhh2, Wlin, blin, (float*)d_out);
}

// Round 4
// 572.766 us; speedup vs baseline: 57.3469x; 1.5600x over previous
//
#include <hip/hip_runtime.h>

#define HH 51
#define TT 256
#define NB 16

typedef __attribute__((ext_vector_type(8))) __bf16 bf16x8;
typedef __attribute__((ext_vector_type(4))) float  floatx4;

#define MFMA16(A, B, C) __builtin_amdgcn_mfma_f32_16x16x32_bf16((A), (B), (C), 0, 0, 0)

__device__ __forceinline__ float rcp_fast(float x) { return __builtin_amdgcn_rcpf(x); }
__device__ __forceinline__ float sigm(float x) { return rcp_fast(1.0f + __expf(-x)); }
__device__ __forceinline__ float tanh_fast(float x) {
    x = fminf(15.0f, fmaxf(-15.0f, x));
    float e = __expf(2.0f * x);
    return 1.0f - 2.0f * rcp_fast(e + 1.0f);   // (e-1)/(e+1)
}

// RNE f32->bf16 (prep only; main kernel uses truncating split)
__device__ __forceinline__ unsigned short f2bf(float f) {
    unsigned u = __float_as_uint(f);
    unsigned r = (u + 0x7FFFu + ((u >> 16) & 1u)) >> 16;
    return (unsigned short)r;
}
__device__ __forceinline__ float bf2f(unsigned short h) {
    return __uint_as_float(((unsigned)h) << 16);
}

// -------------------------------------------------------------------------
// Weight pre-pack into MFMA B-fragments (hi/lo bf16 split), zero-padded.
// B-frag 16x16x32: lane holds B[k=(lane>>4)*8+jj][n=lane&15].
// frag ids: cell1 (K=64):  ((g*4+U)*2+s)*2+hl            (64 frags)
//           cell2 (K=128): 64 + ((g*4+U)*4+s)*2+hl       (128 frags)
//           head  (K=64):  192 + s*2+hl  (B[k][0]=Wlin[k], other cols 0)
// ws bytes: 196 frags * 64 lanes * 16 B = 200704.
// -------------------------------------------------------------------------
__global__ void lstm_prep(const float* __restrict__ Whh1,
                          const float* __restrict__ Wih2, const float* __restrict__ Whh2,
                          const float* __restrict__ Wlin,
                          uint4* __restrict__ frags) {
    int tid = blockIdx.x * blockDim.x + threadIdx.x;
    if (tid >= 196 * 64) return;
    int f = tid >> 6, lane = tid & 63;
    int n = lane & 15, qq = lane >> 4;
    int hl, s, tau, cell;
    if (f < 64)       { cell = 1; int r = f;       hl = r & 1; r >>= 1; s = r & 1; tau = r >> 1; }
    else if (f < 192) { cell = 2; int r = f - 64;  hl = r & 1; r >>= 1; s = r & 3; tau = r >> 2; }
    else              { cell = 3; int r = f - 192; hl = r & 1; s = r >> 1; tau = 0; }
    int g = tau >> 2, U = tau & 3, u = U * 16 + n;
    unsigned int dw[4];
    for (int d = 0; d < 4; d++) {
        unsigned int packed = 0;
        for (int e = 0; e < 2; e++) {
            int jj = d * 2 + e;
            int k = s * 32 + qq * 8 + jj;
            float val = 0.f;
            if (cell == 1) {
                if (u < HH && k < HH) val = Whh1[(g * HH + u) * HH + k];
            } else if (cell == 2) {
                if (u < HH) {
                    if (k < 64) { if (k < HH) val = Wih2[(g * HH + u) * HH + k]; }
                    else        { int k2 = k - 64; if (k2 < HH) val = Whh2[(g * HH + u) * HH + k2]; }
                }
            } else {
                if (n == 0 && k < HH) val = Wlin[k];
            }
            unsigned short hi = f2bf(val);
            unsigned short bits = hl ? f2bf(val - bf2f(hi)) : hi;
            packed |= ((unsigned int)bits) << (16 * e);
        }
        dw[d] = packed;
    }
    frags[f * 64 + lane] = make_uint4(dw[0], dw[1], dw[2], dw[3]);
}

// -------------------------------------------------------------------------
// Persistent LSTM: 1 WG = 16 batch, 512 thr = 8 waves (2 waves/SIMD).
// MFMA role: wave w owns gate g=w&3 for u-groups U in {w>>2, (w>>2)+2}
//   (2 tiles, shared A-frags). Gates round-trip LDS as fp32 (b128 rows).
// Update role: thread owns (u = tid>>3, b = 2*(tid&7)+{0,1}); c in regs.
// h stored as bf16 hi/lo, swizzled col u' = (u + 8*(b>>1)) & 63:
//   writes <=2-way banks, A-frag b128 reads stay 8-phase minimum, 16B aligned.
// 3 barriers/step (g1buf/g2buf split removes the 4th).
// Head: wave 7 runs 6 extra MFMAs over h2(old) in cell2's k-loop ->
//   out[.,t-1]; epilogue computes t=TT-1.
// -------------------------------------------------------------------------
__launch_bounds__(512, 2)
__global__ void lstm_main(const float* __restrict__ input,
                          const uint4* __restrict__ frags,
                          const float* __restrict__ Wih1,
                          const float* __restrict__ bih1, const float* __restrict__ bhh1,
                          const float* __restrict__ bih2, const float* __restrict__ bhh2,
                          const float* __restrict__ blin,
                          float* __restrict__ out) {
    __shared__ __align__(16) unsigned short h1h[16][72], h1l[16][72];
    __shared__ __align__(16) unsigned short h2h[16][72], h2l[16][72];
    __shared__ __align__(16) float g1buf[4 * 64 * 16];
    __shared__ __align__(16) float g2buf[4 * 64 * 16];
    __shared__ float xb[16 * 257];

    const int tid  = threadIdx.x;
    const int lane = tid & 63;
    const int w    = tid >> 6;
    const int l15  = lane & 15;
    const int q    = lane >> 4;
    const int b0   = blockIdx.x * NB;
    const int g    = w & 3;
    const int Ub   = w >> 2;          // tiles U = Ub, Ub+2

    // update-role indices
    const int uu    = tid >> 3;       // 0..63
    const int bpair = (tid & 7) * 2;  // b, b+1
    const bool uval = (uu < HH);
    const int usw   = (uu + 8 * (tid & 7)) & 63;   // swizzled col (b>>1 == tid&7)

    for (int i = tid; i < 16 * 72; i += 512) {
        ((unsigned short*)h1h)[i] = 0; ((unsigned short*)h1l)[i] = 0;
        ((unsigned short*)h2h)[i] = 0; ((unsigned short*)h2l)[i] = 0;
    }
    for (int c = 0; c < 2; c++) {
        int flat = (tid + c * 512) * 4;
        int b = flat >> 8, t0 = flat & 255;
        float4 v = *(const float4*)&input[(size_t)(b0 + b) * TT + t0];
        xb[b * 257 + t0 + 0] = v.x; xb[b * 257 + t0 + 1] = v.y;
        xb[b * 257 + t0 + 2] = v.z; xb[b * 257 + t0 + 3] = v.w;
    }

    // weight-stationary fragments
    bf16x8 B1h[2][2], B1l[2][2], B2h[2][4], B2l[2][4], Hh[2], Hl[2];
    float wxv[2];
#pragma unroll
    for (int ta = 0; ta < 2; ta++) {
        int tau = g * 4 + (Ub + 2 * ta);
#pragma unroll
        for (int s = 0; s < 2; s++) {
            B1h[ta][s] = __builtin_bit_cast(bf16x8, frags[((tau * 2 + s) * 2 + 0) * 64 + lane]);
            B1l[ta][s] = __builtin_bit_cast(bf16x8, frags[((tau * 2 + s) * 2 + 1) * 64 + lane]);
        }
#pragma unroll
        for (int s = 0; s < 4; s++) {
            B2h[ta][s] = __builtin_bit_cast(bf16x8, frags[(64 + (tau * 4 + s) * 2 + 0) * 64 + lane]);
            B2l[ta][s] = __builtin_bit_cast(bf16x8, frags[(64 + (tau * 4 + s) * 2 + 1) * 64 + lane]);
        }
        int ucol = (Ub + 2 * ta) * 16 + l15;
        wxv[ta] = (ucol < HH) ? Wih1[g * HH + ucol] : 0.f;
    }
#pragma unroll
    for (int s = 0; s < 2; s++) {
        Hh[s] = __builtin_bit_cast(bf16x8, frags[(192 + s * 2 + 0) * 64 + lane]);
        Hl[s] = __builtin_bit_cast(bf16x8, frags[(192 + s * 2 + 1) * 64 + lane]);
    }
    float b1u[4], b2u[4];
#pragma unroll
    for (int gg = 0; gg < 4; gg++) {
        b1u[gg] = uval ? (bih1[gg * HH + uu] + bhh1[gg * HH + uu]) : 0.f;
        b2u[gg] = uval ? (bih2[gg * HH + uu] + bhh2[gg * HH + uu]) : 0.f;
    }
    const float bl = blin[0];
    float c1[2] = {0.f, 0.f}, c2[2] = {0.f, 0.f};
    const int swq = 8 * (l15 >> 1);
    const int row0 = (g * 64 + Ub * 16 + l15) * 16 + q * 4;
    const int row1 = (g * 64 + (Ub + 2) * 16 + l15) * 16 + q * 4;

    __syncthreads();

    for (int t = 0; t < TT; t++) {
        // ---------------- P1: cell1 MFMA -> g1buf -------------------------
        float xr0 = xb[(q * 4 + 0) * 257 + t], xr1 = xb[(q * 4 + 1) * 257 + t];
        float xr2 = xb[(q * 4 + 2) * 257 + t], xr3 = xb[(q * 4 + 3) * 257 + t];
        floatx4 a0 = {xr0 * wxv[0], xr1 * wxv[0], xr2 * wxv[0], xr3 * wxv[0]};
        floatx4 a1 = {xr0 * wxv[1], xr1 * wxv[1], xr2 * wxv[1], xr3 * wxv[1]};
#pragma unroll
        for (int s = 0; s < 2; s++) {
            int st = (s * 32 + q * 8 + swq) & 63;
            bf16x8 ah = *(const bf16x8*)&h1h[l15][st];
            bf16x8 al = *(const bf16x8*)&h1l[l15][st];
            a0 = MFMA16(ah, B1h[0][s], a0); a0 = MFMA16(ah, B1l[0][s], a0); a0 = MFMA16(al, B1h[0][s], a0);
            a1 = MFMA16(ah, B1h[1][s], a1); a1 = MFMA16(ah, B1l[1][s], a1); a1 = MFMA16(al, B1h[1][s], a1);
        }
        *(floatx4*)&g1buf[row0] = a0;
        *(floatx4*)&g1buf[row1] = a1;
        __syncthreads();

        // ---------------- P3: update1 (gates1 -> h1) ----------------------
        if (uval) {
#pragma unroll
            for (int pp = 0; pp < 2; pp++) {
                int b = bpair + pp;
                float gi = g1buf[(0 * 64 + uu) * 16 + b] + b1u[0];
                float gf = g1buf[(1 * 64 + uu) * 16 + b] + b1u[1];
                float gG = g1buf[(2 * 64 + uu) * 16 + b] + b1u[2];
                float go = g1buf[(3 * 64 + uu) * 16 + b] + b1u[3];
                float cn = sigm(gf) * c1[pp] + sigm(gi) * tanh_fast(gG);
                c1[pp] = cn;
                float h = sigm(go) * tanh_fast(cn);
                unsigned hb = __float_as_uint(h);
                unsigned short hi = (unsigned short)(hb >> 16);
                float lof = h - __uint_as_float(hb & 0xFFFF0000u);
                unsigned short lo = (unsigned short)(__float_as_uint(lof) >> 16);
                h1h[b][usw] = hi; h1l[b][usw] = lo;
            }
        }
        __syncthreads();

        // ---------------- P4: cell2 MFMA (+head on wave 7) -> g2buf -------
        floatx4 d0 = {0.f, 0.f, 0.f, 0.f}, d1 = {0.f, 0.f, 0.f, 0.f};
        floatx4 ho = {0.f, 0.f, 0.f, 0.f};
#pragma unroll
        for (int s = 0; s < 4; s++) {
            int st = ((s & 1) * 32 + q * 8 + swq) & 63;
            bf16x8 ah, al;
            if (s < 2) { ah = *(const bf16x8*)&h1h[l15][st]; al = *(const bf16x8*)&h1l[l15][st]; }
            else       { ah = *(const bf16x8*)&h2h[l15][st]; al = *(const bf16x8*)&h2l[l15][st]; }
            d0 = MFMA16(ah, B2h[0][s], d0); d0 = MFMA16(ah, B2l[0][s], d0); d0 = MFMA16(al, B2h[0][s], d0);
            d1 = MFMA16(ah, B2h[1][s], d1); d1 = MFMA16(ah, B2l[1][s], d1); d1 = MFMA16(al, B2h[1][s], d1);
            if (w == 7 && s >= 2) {
                int s2 = s - 2;
                ho = MFMA16(ah, Hh[s2], ho); ho = MFMA16(ah, Hl[s2], ho); ho = MFMA16(al, Hh[s2], ho);
            }
        }
        *(floatx4*)&g2buf[row0] = d0;
        *(floatx4*)&g2buf[row1] = d1;
        if (w == 7 && l15 == 0 && t > 0) {
#pragma unroll
            for (int r = 0; r < 4; r++)
                out[(size_t)(b0 + q * 4 + r) * TT + (t - 1)] = ho[r] + bl;
        }
        __syncthreads();

        // ---------------- P6: update2 (gates2 -> h2); no trailing barrier --
        if (uval) {
#pragma unroll
            for (int pp = 0; pp < 2; pp++) {
                int b = bpair + pp;
                float gi = g2buf[(0 * 64 + uu) * 16 + b] + b2u[0];
                float gf = g2buf[(1 * 64 + uu) * 16 + b] + b2u[1];
                float gG = g2buf[(2 * 64 + uu) * 16 + b] + b2u[2];
                float go = g2buf[(3 * 64 + uu) * 16 + b] + b2u[3];
                float cn = sigm(gf) * c2[pp] + sigm(gi) * tanh_fast(gG);
                c2[pp] = cn;
                float h = sigm(go) * tanh_fast(cn);
                unsigned hb = __float_as_uint(h);
                unsigned short hi = (unsigned short)(hb >> 16);
                float lof = h - __uint_as_float(hb & 0xFFFF0000u);
                unsigned short lo = (unsigned short)(__float_as_uint(lof) >> 16);
                h2h[b][usw] = hi; h2l[b][usw] = lo;
            }
        }
        // next P1 touches only h1/xb/g1buf; h2/g2buf re-read only after
        // two barriers -> safe with 3 barriers/step.
    }

    // ---------------- epilogue: out[:, TT-1] from final h2 ----------------
    __syncthreads();
    if (w == 7) {
        floatx4 ho = {0.f, 0.f, 0.f, 0.f};
#pragma unroll
        for (int s = 0; s < 2; s++) {
            int st = (s * 32 + q * 8 + swq) & 63;
            bf16x8 ah = *(const bf16x8*)&h2h[l15][st];
            bf16x8 al = *(const bf16x8*)&h2l[l15][st];
            ho = MFMA16(ah, Hh[s], ho); ho = MFMA16(ah, Hl[s], ho); ho = MFMA16(al, Hh[s], ho);
        }
        if (l15 == 0) {
#pragma unroll
            for (int r = 0; r < 4; r++)
                out[(size_t)(b0 + q * 4 + r) * TT + (TT - 1)] = ho[r] + bl;
        }
    }
}

extern "C" void kernel_launch(void* const* d_in, const int* in_sizes, int n_in,
                              void* d_out, int out_size, void* d_ws, size_t ws_size,
                              hipStream_t stream) {
    const float* input = (const float*)d_in[0];
    const float* Wih1  = (const float*)d_in[1];
    const float* Whh1  = (const float*)d_in[2];
    const float* bih1  = (const float*)d_in[3];
    const float* bhh1  = (const float*)d_in[4];
    const float* Wih2  = (const float*)d_in[5];
    const float* Whh2  = (const float*)d_in[6];
    const float* bih2  = (const float*)d_in[7];
    const float* bhh2  = (const float*)d_in[8];
    const float* Wlin  = (const float*)d_in[9];
    const float* blin  = (const float*)d_in[10];

    uint4* frags = (uint4*)d_ws;            // 196 frags * 1 KiB = 200704 B
    int B = in_sizes[0] / TT;               // 4096

    lstm_prep<<<49, 256, 0, stream>>>(Whh1, Wih2, Whh2, Wlin, frags);
    lstm_main<<<B / NB, 512, 0, stream>>>(input, frags, Wih1, bih1, bhh1,
                                          bih2, bhh2, blin, (float*)d_out);
}

// Round 5
// 490.107 us; speedup vs baseline: 67.0187x; 1.1687x over previous
//
#include <hip/hip_runtime.h>

#define HH 51
#define TT 256
#define NB 16
#define USTG 20          // gate-buffer u-stride in dwords (16 batch + 4 pad)

typedef __attribute__((ext_vector_type(8))) __bf16 bf16x8;
typedef __attribute__((ext_vector_type(4))) float  floatx4;

#define MFMA16(A,B,C) __builtin_amdgcn_mfma_f32_16x16x32_bf16((A),(B),(C),0,0,0)

__device__ __forceinline__ float rcp_fast(float x) { return __builtin_amdgcn_rcpf(x); }
__device__ __forceinline__ float sigm(float x) { return rcp_fast(1.0f + __expf(-x)); }
__device__ __forceinline__ float tanh_fast(float x) {
    x = fminf(15.0f, fmaxf(-15.0f, x));
    float e = __expf(2.0f * x);
    return 1.0f - 2.0f * rcp_fast(e + 1.0f);
}
__device__ __forceinline__ unsigned short f2bf(float f) {
    unsigned u = __float_as_uint(f);
    unsigned r = (u + 0x7FFFu + ((u >> 16) & 1u)) >> 16;
    return (unsigned short)r;
}
__device__ __forceinline__ float bf2f(unsigned short h) {
    return __uint_as_float(((unsigned)h) << 16);
}

// ------------- weight pre-pack (identical layout to round 4) -------------
// B-frag 16x16x32: lane holds B[k=(lane>>4)*8+jj][n=lane&15].
// ids: cell1 ((g*4+U)*2+s)*2+hl (64) | cell2 64+((g*4+U)*4+s)*2+hl (128) |
//      head 192+s*2+hl (4). ws = 196*64*16 B.
__global__ void lstm_prep(const float* __restrict__ Whh1,
                          const float* __restrict__ Wih2, const float* __restrict__ Whh2,
                          const float* __restrict__ Wlin,
                          uint4* __restrict__ frags) {
    int tid = blockIdx.x * blockDim.x + threadIdx.x;
    if (tid >= 196 * 64) return;
    int f = tid >> 6, lane = tid & 63;
    int n = lane & 15, qq = lane >> 4;
    int hl, s, tau, cell;
    if (f < 64)       { cell = 1; int r = f;       hl = r & 1; r >>= 1; s = r & 1; tau = r >> 1; }
    else if (f < 192) { cell = 2; int r = f - 64;  hl = r & 1; r >>= 1; s = r & 3; tau = r >> 2; }
    else              { cell = 3; int r = f - 192; hl = r & 1; s = r >> 1; tau = 0; }
    int g = tau >> 2, U = tau & 3, u = U * 16 + n;
    unsigned int dw[4];
    for (int d = 0; d < 4; d++) {
        unsigned int packed = 0;
        for (int e = 0; e < 2; e++) {
            int jj = d * 2 + e;
            int k = s * 32 + qq * 8 + jj;
            float val = 0.f;
            if (cell == 1) {
                if (u < HH && k < HH) val = Whh1[(g * HH + u) * HH + k];
            } else if (cell == 2) {
                if (u < HH) {
                    if (k < 64) { if (k < HH) val = Wih2[(g * HH + u) * HH + k]; }
                    else        { int k2 = k - 64; if (k2 < HH) val = Whh2[(g * HH + u) * HH + k2]; }
                }
            } else {
                if (n == 0 && k < HH) val = Wlin[k];
            }
            unsigned short hi = f2bf(val);
            unsigned short bits = hl ? f2bf(val - bf2f(hi)) : hi;
            packed |= ((unsigned int)bits) << (16 * e);
        }
        dw[d] = packed;
    }
    frags[f * 64 + lane] = make_uint4(dw[0], dw[1], dw[2], dw[3]);
}

// -------------------------------------------------------------------------
// Producer-consumer persistent LSTM. 512 thr = 8 waves, 1 WG/CU.
// Waves 0-3 (mf): cell2 MFMA (gate w, tiles U0-3) + head (wave 0), phase A.
// Waves 4-7 (upd): update1 (phase A); cell1(t+1) MFMA (gate w-4) + update2
//   (phase B). c1/c2 live in upd-thread registers.
// Skew: A(it): cell2(it-1)->g2, head out(it-2), update1(it)->h1[it&1]
//       B(it): cell1(it+1)->g1, update2(it-1)->h2[(it-1)&1]
// h arrays: uint-packed bf16 pairs [parity][b][36], swizzled
//   uidx = ((u>>1) + 4*(b>>1)) & 31; A-frag reads stay b128-contiguous.
// Gate bufs [g][u][b] with u-stride 20 dwords: float2 reads ~2-way banks.
// -------------------------------------------------------------------------
__launch_bounds__(512, 2)
__global__ void lstm_main(const float* __restrict__ input,
                          const uint4* __restrict__ frags,
                          const float* __restrict__ Wih1,
                          const float* __restrict__ bih1, const float* __restrict__ bhh1,
                          const float* __restrict__ bih2, const float* __restrict__ bhh2,
                          const float* __restrict__ blin,
                          float* __restrict__ out) {
    __shared__ __align__(16) unsigned int h1h[2][16][36], h1l[2][16][36];
    __shared__ __align__(16) unsigned int h2h[2][16][36], h2l[2][16][36];
    __shared__ __align__(16) float g1buf[4 * 64 * USTG];
    __shared__ __align__(16) float g2buf[4 * 64 * USTG];
    __shared__ float xb[16 * 257];

    const int tid  = threadIdx.x;
    const int lane = tid & 63;
    const int w    = tid >> 6;
    const int l15  = lane & 15;
    const int q    = lane >> 4;
    const int b0g  = blockIdx.x * NB;
    const bool mf  = (w < 4);

    for (int i = tid; i < 2 * 16 * 36; i += 512) {
        ((unsigned*)h1h)[i] = 0; ((unsigned*)h1l)[i] = 0;
        ((unsigned*)h2h)[i] = 0; ((unsigned*)h2l)[i] = 0;
    }
    for (int c = 0; c < 2; c++) {
        int flat = (tid + c * 512) * 4;
        int b = flat >> 8, t0 = flat & 255;
        float4 v = *(const float4*)&input[(size_t)(b0g + b) * TT + t0];
        xb[b * 257 + t0 + 0] = v.x; xb[b * 257 + t0 + 1] = v.y;
        xb[b * 257 + t0 + 2] = v.z; xb[b * 257 + t0 + 3] = v.w;
    }

    // Union fragment file: mf waves use fr[0..31] = B2, fr[32..35] = head;
    // upd waves use fr[0..15] = B1. Keeps worst-path registers bounded.
    bf16x8 fr[36];
    float bcol[4], wxv[4];
    if (mf) {
#pragma unroll
        for (int U = 0; U < 4; U++) {
            int tau = w * 4 + U;
#pragma unroll
            for (int s = 0; s < 4; s++) {
                fr[U * 8 + s * 2 + 0] = __builtin_bit_cast(bf16x8, frags[(64 + (tau * 4 + s) * 2 + 0) * 64 + lane]);
                fr[U * 8 + s * 2 + 1] = __builtin_bit_cast(bf16x8, frags[(64 + (tau * 4 + s) * 2 + 1) * 64 + lane]);
            }
            int uc = U * 16 + l15;
            bcol[U] = (uc < HH) ? (bih2[w * HH + uc] + bhh2[w * HH + uc]) : 0.f;
            wxv[U] = 0.f;
        }
        if (w == 0) {
#pragma unroll
            for (int s = 0; s < 2; s++) {
                fr[32 + s * 2 + 0] = __builtin_bit_cast(bf16x8, frags[(192 + s * 2 + 0) * 64 + lane]);
                fr[32 + s * 2 + 1] = __builtin_bit_cast(bf16x8, frags[(192 + s * 2 + 1) * 64 + lane]);
            }
        }
    } else {
        int g = w - 4;
#pragma unroll
        for (int U = 0; U < 4; U++) {
            int tau = g * 4 + U;
#pragma unroll
            for (int s = 0; s < 2; s++) {
                fr[U * 4 + s * 2 + 0] = __builtin_bit_cast(bf16x8, frags[((tau * 2 + s) * 2 + 0) * 64 + lane]);
                fr[U * 4 + s * 2 + 1] = __builtin_bit_cast(bf16x8, frags[((tau * 2 + s) * 2 + 1) * 64 + lane]);
            }
            int uc = U * 16 + l15;
            bcol[U] = (uc < HH) ? (bih1[g * HH + uc] + bhh1[g * HH + uc]) : 0.f;
            wxv[U]  = (uc < HH) ? Wih1[g * HH + uc] : 0.f;
        }
    }
    const float bl = blin[0];

    // update-role constants: thread owns u in {U0,U0+1}, b in {b0,b0+1}
    const int U0 = 2 * ((lane >> 3) + 8 * (w & 3));
    const int b0 = 2 * (lane & 7);
    const int e8 = lane & 7;                  // b0>>1
    const int uidx = ((U0 >> 1) + 4 * e8) & 31;
    float c1[4] = {0.f, 0.f, 0.f, 0.f}, c2[4] = {0.f, 0.f, 0.f, 0.f};

    __syncthreads();

    // prologue: g1(0) = x(0)*Wih1 + b1 (h1(-1)=0, no MFMA needed)
    if (!mf) {
        float xr[4];
#pragma unroll
        for (int r = 0; r < 4; r++) xr[r] = xb[(q * 4 + r) * 257 + 0];
#pragma unroll
        for (int U = 0; U < 4; U++) {
            floatx4 a;
#pragma unroll
            for (int r = 0; r < 4; r++) a[r] = fmaf(xr[r], wxv[U], bcol[U]);
            *(floatx4*)&g1buf[((w - 4) * 64 + U * 16 + l15) * USTG + q * 4] = a;
        }
    }
    __syncthreads();

    for (int it = 0; it <= TT + 1; it++) {
        // ================= PHASE A =================
        if (mf) {
            if (it >= 1) {
                const int ph1 = (it + 1) & 1, ph2 = it & 1;
                floatx4 d[4];
#pragma unroll
                for (int U = 0; U < 4; U++)
                    d[U] = (floatx4){bcol[U], bcol[U], bcol[U], bcol[U]};
                floatx4 ho = {0.f, 0.f, 0.f, 0.f};
#pragma unroll
                for (int s = 0; s < 4; s++) {
                    int base = ((s & 1) * 16 + q * 4 + 4 * (l15 >> 1)) & 31;
                    bf16x8 ah, al;
                    if (s < 2) { ah = *(const bf16x8*)&h1h[ph1][l15][base];
                                 al = *(const bf16x8*)&h1l[ph1][l15][base]; }
                    else       { ah = *(const bf16x8*)&h2h[ph2][l15][base];
                                 al = *(const bf16x8*)&h2l[ph2][l15][base]; }
#pragma unroll
                    for (int U = 0; U < 4; U++) {
                        d[U] = MFMA16(ah, fr[U * 8 + s * 2 + 0], d[U]);
                        d[U] = MFMA16(ah, fr[U * 8 + s * 2 + 1], d[U]);
                        d[U] = MFMA16(al, fr[U * 8 + s * 2 + 0], d[U]);
                    }
                    if (w == 0 && s >= 2) {
                        ho = MFMA16(ah, fr[32 + (s - 2) * 2 + 0], ho);
                        ho = MFMA16(ah, fr[32 + (s - 2) * 2 + 1], ho);
                        ho = MFMA16(al, fr[32 + (s - 2) * 2 + 0], ho);
                    }
                }
#pragma unroll
                for (int U = 0; U < 4; U++)
                    *(floatx4*)&g2buf[(w * 64 + U * 16 + l15) * USTG + q * 4] = d[U];
                if (w == 0 && l15 == 0 && it >= 2) {
#pragma unroll
                    for (int r = 0; r < 4; r++)
                        out[(size_t)(b0g + q * 4 + r) * TT + (it - 2)] = ho[r] + bl;
                }
            }
        } else {
            if (it < TT) {                    // update1(it) -> h1[it&1]
                const int ph = it & 1;
                float2 G[2][4];
#pragma unroll
                for (int iu = 0; iu < 2; iu++)
#pragma unroll
                    for (int g = 0; g < 4; g++)
                        G[iu][g] = *(const float2*)&g1buf[(g * 64 + U0 + iu) * USTG + b0];
                unsigned hhi[2] = {0u, 0u}, hlo[2] = {0u, 0u};
#pragma unroll
                for (int iu = 0; iu < 2; iu++) {
#pragma unroll
                    for (int pb = 0; pb < 2; pb++) {
                        float gi = pb ? G[iu][0].y : G[iu][0].x;
                        float gf = pb ? G[iu][1].y : G[iu][1].x;
                        float gG = pb ? G[iu][2].y : G[iu][2].x;
                        float go = pb ? G[iu][3].y : G[iu][3].x;
                        float cn = sigm(gf) * c1[iu * 2 + pb] + sigm(gi) * tanh_fast(gG);
                        c1[iu * 2 + pb] = cn;
                        float h = sigm(go) * tanh_fast(cn);
                        unsigned hb = __float_as_uint(h);
                        unsigned hi16 = hb >> 16;
                        float lof = h - __uint_as_float(hb & 0xFFFF0000u);
                        unsigned lo16 = __float_as_uint(lof) >> 16;
                        hhi[pb] |= hi16 << (16 * iu);
                        hlo[pb] |= lo16 << (16 * iu);
                    }
                }
#pragma unroll
                for (int pb = 0; pb < 2; pb++) {
                    h1h[ph][b0 + pb][uidx] = hhi[pb];
                    h1l[ph][b0 + pb][uidx] = hlo[pb];
                }
            }
        }
        __syncthreads();

        // ================= PHASE B =================
        if (!mf) {
            if (it <= TT - 2) {               // cell1(it+1) -> g1buf
                const int ph = it & 1;
                float xr[4];
#pragma unroll
                for (int r = 0; r < 4; r++) xr[r] = xb[(q * 4 + r) * 257 + it + 1];
                floatx4 a[4];
#pragma unroll
                for (int U = 0; U < 4; U++)
#pragma unroll
                    for (int r = 0; r < 4; r++) a[U][r] = fmaf(xr[r], wxv[U], bcol[U]);
#pragma unroll
                for (int s = 0; s < 2; s++) {
                    int base = (s * 16 + q * 4 + 4 * (l15 >> 1)) & 31;
                    bf16x8 ah = *(const bf16x8*)&h1h[ph][l15][base];
                    bf16x8 al = *(const bf16x8*)&h1l[ph][l15][base];
#pragma unroll
                    for (int U = 0; U < 4; U++) {
                        a[U] = MFMA16(ah, fr[U * 4 + s * 2 + 0], a[U]);
                        a[U] = MFMA16(ah, fr[U * 4 + s * 2 + 1], a[U]);
                        a[U] = MFMA16(al, fr[U * 4 + s * 2 + 0], a[U]);
                    }
                }
#pragma unroll
                for (int U = 0; U < 4; U++)
                    *(floatx4*)&g1buf[((w - 4) * 64 + U * 16 + l15) * USTG + q * 4] = a[U];
            }
            if (it >= 1 && it <= TT) {        // update2(it-1) -> h2[(it-1)&1]
                const int ph = (it - 1) & 1;
                float2 G[2][4];
#pragma unroll
                for (int iu = 0; iu < 2; iu++)
#pragma unroll
                    for (int g = 0; g < 4; g++)
                        G[iu][g] = *(const float2*)&g2buf[(g * 64 + U0 + iu) * USTG + b0];
                unsigned hhi[2] = {0u, 0u}, hlo[2] = {0u, 0u};
#pragma unroll
                for (int iu = 0; iu < 2; iu++) {
#pragma unroll
                    for (int pb = 0; pb < 2; pb++) {
                        float gi = pb ? G[iu][0].y : G[iu][0].x;
                        float gf = pb ? G[iu][1].y : G[iu][1].x;
                        float gG = pb ? G[iu][2].y : G[iu][2].x;
                        float go = pb ? G[iu][3].y : G[iu][3].x;
                        float cn = sigm(gf) * c2[iu * 2 + pb] + sigm(gi) * tanh_fast(gG);
                        c2[iu * 2 + pb] = cn;
                        float h = sigm(go) * tanh_fast(cn);
                        unsigned hb = __float_as_uint(h);
                        unsigned hi16 = hb >> 16;
                        float lof = h - __uint_as_float(hb & 0xFFFF0000u);
                        unsigned lo16 = __float_as_uint(lof) >> 16;
                        hhi[pb] |= hi16 << (16 * iu);
                        hlo[pb] |= lo16 << (16 * iu);
                    }
                }
#pragma unroll
                for (int pb = 0; pb < 2; pb++) {
                    h2h[ph][b0 + pb][uidx] = hhi[pb];
                    h2l[ph][b0 + pb][uidx] = hlo[pb];
                }
            }
        }
        __syncthreads();
    }
}

extern "C" void kernel_launch(void* const* d_in, const int* in_sizes, int n_in,
                              void* d_out, int out_size, void* d_ws, size_t ws_size,
                              hipStream_t stream) {
    const float* input = (const float*)d_in[0];
    const float* Wih1  = (const float*)d_in[1];
    const float* Whh1  = (const float*)d_in[2];
    const float* bih1  = (const float*)d_in[3];
    const float* bhh1  = (const float*)d_in[4];
    const float* Wih2  = (const float*)d_in[5];
    const float* Whh2  = (const float*)d_in[6];
    const float* bih2  = (const float*)d_in[7];
    const float* bhh2  = (const float*)d_in[8];
    const float* Wlin  = (const float*)d_in[9];
    const float* blin  = (const float*)d_in[10];

    uint4* frags = (uint4*)d_ws;            // 196 frags * 1 KiB
    int B = in_sizes[0] / TT;               // 4096

    lstm_prep<<<49, 256, 0, stream>>>(Whh1, Wih2, Whh2, Wlin, frags);
    lstm_main<<<B / NB, 512, 0, stream>>>(input, frags, Wih1, bih1, bhh1,
                                          bih2, bhh2, blin, (float*)d_out);
}